// Round 6
// baseline (432.668 us; speedup 1.0000x reference)
//
#include <hip/hip_runtime.h>

#define Bn 16
#define Sn 64
#define Cn 20
#define Tn 2048
#define TPB 256

// Rank-1 MLP layer for 4 time points. Weight/bias reads are wave-uniform ->
// compiler emits s_load (SMEM pipe), freeing VALU+LDS for the FMAs.
template <int NI, int NJ>
__device__ __forceinline__ void layerU(const float (&in)[4][20], float (&out)[4][20],
                                       const float* __restrict__ W,
                                       const float* __restrict__ bb) {
    #pragma unroll
    for (int j = 0; j < NJ; ++j) {
        const float bj = bb[j];
        #pragma unroll
        for (int m = 0; m < 4; ++m) out[m][j] = bj;
    }
    #pragma unroll
    for (int c = 0; c < NI; ++c) {
        #pragma unroll
        for (int j = 0; j < NJ; ++j) {
            const float w = W[c * NJ + j];   // uniform, contiguous in j -> s_load_dwordx4
            #pragma unroll
            for (int m = 0; m < 4; ++m) out[m][j] = fmaf(in[m][c], w, out[m][j]);
        }
    }
    #pragma unroll
    for (int j = 0; j < NJ; ++j) {
        #pragma unroll
        for (int m = 0; m < 4; ++m) out[m][j] = fmaxf(out[m][j], 0.f);
    }
}

// ---------------- Kernel A: per-time-point MLP (fp32), fp64 row sums ----------------
// grid = B*S blocks, 256 threads; each thread 4 consecutive t, 2 passes.
__global__ __launch_bounds__(256) void mlp_kernel(
    const float* __restrict__ data,
    const float* __restrict__ W1, const float* __restrict__ b1,
    const float* __restrict__ W2, const float* __restrict__ b2,
    const float* __restrict__ W3, const float* __restrict__ b3,
    const float* __restrict__ W4, const float* __restrict__ b4,
    const float* __restrict__ W5, const float* __restrict__ b5,
    float* __restrict__ y, double* __restrict__ R)
{
    __shared__ double rbuf[TPB];

    const int tid = threadIdx.x;
    const int bs = blockIdx.x;                       // b*S + s
    const float* base = data + (size_t)bs * Cn * Tn; // [c][t]
    float* yrow = y + (size_t)bs * Tn;

    double lsum = 0.0;
    for (int pass = 0; pass < Tn / (TPB * 4); ++pass) {
        const int t0 = (pass * TPB + tid) * 4;
        float x[4][20], h[4][20];
        #pragma unroll
        for (int c = 0; c < 20; ++c) {
            const float4 v = *(const float4*)&base[c * Tn + t0];
            x[0][c] = v.x; x[1][c] = v.y; x[2][c] = v.z; x[3][c] = v.w;
        }

        layerU<20, 20>(x, h, W1, b1);
        layerU<20, 20>(h, x, W2, b2);
        layerU<20, 20>(x, h, W3, b3);
        layerU<20, 10>(h, x, W4, b4);

        float yv[4];
        const float bb5 = b5[0];
        #pragma unroll
        for (int m = 0; m < 4; ++m) {  // 10 -> 1
            float yy = bb5;
            #pragma unroll
            for (int i = 0; i < 10; ++i) yy = fmaf(x[m][i], W5[i], yy);
            yy = fmaxf(yy, 0.f);
            yv[m] = yy;
            lsum += (double)yy;
        }
        float4 st; st.x = yv[0]; st.y = yv[1]; st.z = yv[2]; st.w = yv[3];
        *(float4*)&yrow[t0] = st;
    }

    // block reduction (LDS tree) -> row SUM in fp64
    rbuf[tid] = lsum;
    __syncthreads();
    for (int off = 128; off > 0; off >>= 1) {
        if (tid < off) rbuf[tid] += rbuf[tid + off];
        __syncthreads();
    }
    if (tid == 0) R[bs] = rbuf[0];
}

// ---------------- Kernel B: covariance rows, fp64, 4-u groups per wave ----------------
// grid = B*S blocks (one per (b,s)); wave w owns u = w*16 .. w*16+15.
__global__ __launch_bounds__(256) void cov_kernel(
    const float* __restrict__ y, const double* __restrict__ R,
    double* __restrict__ covd)
{
    __shared__ double ysc[Tn];     // centered row s, fp64 (16 KB)
    __shared__ double rbuf[TPB];

    const int tid = threadIdx.x;
    const int lane = tid & 63, wv = tid >> 6;
    const int b = blockIdx.x >> 6;

    const double ms = R[blockIdx.x] * (1.0 / Tn);
    const float* yrow = y + (size_t)blockIdx.x * Tn;

    double lsum = 0.0;
    for (int t = tid; t < Tn; t += TPB) {
        const double v = (double)yrow[t] - ms;
        ysc[t] = v;
        lsum += v;
    }
    rbuf[tid] = lsum;
    __syncthreads();
    for (int off = 128; off > 0; off >>= 1) {
        if (tid < off) rbuf[tid] += rbuf[tid + off];
        __syncthreads();
    }
    const double sumYsc = rbuf[0];   // residual sum of centered row (≈0)

    const float* ybase = y + (size_t)(b << 6) * Tn;
    double* crow = covd + (size_t)blockIdx.x * Sn;
    const double* Rb = R + (b << 6);

    for (int ug = 0; ug < 4; ++ug) {
        const int u0 = wv * 16 + ug * 4;
        const float* yu0 = ybase + (size_t)(u0 + 0) * Tn;
        const float* yu1 = ybase + (size_t)(u0 + 1) * Tn;
        const float* yu2 = ybase + (size_t)(u0 + 2) * Tn;
        const float* yu3 = ybase + (size_t)(u0 + 3) * Tn;
        double a0 = 0.0, a1 = 0.0, a2 = 0.0, a3 = 0.0;
        #pragma unroll
        for (int k = 0; k < Tn / 128; ++k) {
            const int t0 = k * 128 + lane * 2;
            const double s0 = ysc[t0], s1 = ysc[t0 + 1];     // ds_read_b128
            const float2 f0 = *(const float2*)&yu0[t0];
            const float2 f1 = *(const float2*)&yu1[t0];
            const float2 f2 = *(const float2*)&yu2[t0];
            const float2 f3 = *(const float2*)&yu3[t0];
            a0 = fma(s0, (double)f0.x, a0); a0 = fma(s1, (double)f0.y, a0);
            a1 = fma(s0, (double)f1.x, a1); a1 = fma(s1, (double)f1.y, a1);
            a2 = fma(s0, (double)f2.x, a2); a2 = fma(s1, (double)f2.y, a2);
            a3 = fma(s0, (double)f3.x, a3); a3 = fma(s1, (double)f3.y, a3);
        }
        // 4 interleaved wave butterflies (latency overlap)
        #pragma unroll
        for (int off = 32; off; off >>= 1) {
            a0 += __shfl_down(a0, off, 64);
            a1 += __shfl_down(a1, off, 64);
            a2 += __shfl_down(a2, off, 64);
            a3 += __shfl_down(a3, off, 64);
        }
        if (lane == 0) {
            const double inv = 1.0 / (Tn - 1);
            crow[u0 + 0] = (a0 - Rb[u0 + 0] * (1.0 / Tn) * sumYsc) * inv;
            crow[u0 + 1] = (a1 - Rb[u0 + 1] * (1.0 / Tn) * sumYsc) * inv;
            crow[u0 + 2] = (a2 - Rb[u0 + 2] * (1.0 / Tn) * sumYsc) * inv;
            crow[u0 + 3] = (a3 - Rb[u0 + 3] * (1.0 / Tn) * sumYsc) * inv;
        }
    }
}

// ---------------- Kernel C: corr + output (fp64 math, NaN-propagating clip) ----------------
__global__ __launch_bounds__(256) void corr_kernel(
    const double* __restrict__ covd, float* __restrict__ out)
{
    const int i = blockIdx.x * TPB + threadIdx.x;
    if (i >= Bn * Sn * Sn) return;
    const int b = i / (Sn * Sn);
    const int rem = i % (Sn * Sn);
    const int s = rem / Sn, u = rem % Sn;
    const double css = covd[((size_t)b * Sn + s) * Sn + s];
    const double cuu = covd[((size_t)b * Sn + u) * Sn + u];
    const double csu = covd[i];
    double r = csu / sqrt(css * cuu);
    r = (r < -1.0) ? -1.0 : ((r > 1.0) ? 1.0 : r);   // NaN-propagating clip
    out[i] = (float)(1.0 - r);
}

extern "C" void kernel_launch(void* const* d_in, const int* in_sizes, int n_in,
                              void* d_out, int out_size, void* d_ws, size_t ws_size,
                              hipStream_t stream) {
    const float* data = (const float*)d_in[0];
    const float* W1 = (const float*)d_in[1];  const float* b1 = (const float*)d_in[2];
    const float* W2 = (const float*)d_in[3];  const float* b2 = (const float*)d_in[4];
    const float* W3 = (const float*)d_in[5];  const float* b3 = (const float*)d_in[6];
    const float* W4 = (const float*)d_in[7];  const float* b4 = (const float*)d_in[8];
    const float* W5 = (const float*)d_in[9];  const float* b5 = (const float*)d_in[10];
    float* out = (float*)d_out;

    // ws layout: y fp32 (8 MB) | covd fp64 (512 KB) | R fp64 (32 KB)  — proven size
    float* y = (float*)d_ws;
    double* covd = (double*)((char*)d_ws + (size_t)Bn * Sn * Tn * sizeof(float));
    double* R = covd + (size_t)Bn * Sn * Sn;

    mlp_kernel<<<Bn * Sn, TPB, 0, stream>>>(data, W1, b1, W2, b2, W3, b3, W4, b4, W5, b5, y, R);
    cov_kernel<<<Bn * Sn, TPB, 0, stream>>>(y, R, covd);
    corr_kernel<<<(Bn * Sn * Sn + TPB - 1) / TPB, TPB, 0, stream>>>(covd, out);
}

// Round 7
// 316.197 us; speedup vs baseline: 1.3683x; 1.3683x over previous
//
#include <hip/hip_runtime.h>

#define Bn 16
#define Sn 64
#define Cn 20
#define Tn 2048
#define TPB 256

// One MLP layer for 2 time points: in[m][c] -> out[m][j], ReLU.
// WT transposed in LDS: WT[j*20+c], rows 80 B (16B-aligned) -> ds_read_b128.
template <int NJ>
__device__ __forceinline__ void layer2(const float (&in)[2][20], float (&out)[2][20],
                                       const float* __restrict__ WT,
                                       const float* __restrict__ bb) {
    #pragma unroll
    for (int j = 0; j < NJ; ++j) {
        float a0 = bb[j], a1 = bb[j];
        const float4* wr = (const float4*)(WT + j * 20);
        #pragma unroll
        for (int q = 0; q < 5; ++q) {
            const float4 w = wr[q];
            a0 = fmaf(in[0][4 * q + 0], w.x, a0);  a1 = fmaf(in[1][4 * q + 0], w.x, a1);
            a0 = fmaf(in[0][4 * q + 1], w.y, a0);  a1 = fmaf(in[1][4 * q + 1], w.y, a1);
            a0 = fmaf(in[0][4 * q + 2], w.z, a0);  a1 = fmaf(in[1][4 * q + 2], w.z, a1);
            a0 = fmaf(in[0][4 * q + 3], w.w, a0);  a1 = fmaf(in[1][4 * q + 3], w.w, a1);
        }
        out[0][j] = fmaxf(a0, 0.f);
        out[1][j] = fmaxf(a1, 0.f);
    }
}

// ---------------- Kernel A: MLP. grid = B*S*4; block does 512 t of one row ----------------
__global__ __launch_bounds__(256) void mlp_kernel(
    const float* __restrict__ data,
    const float* __restrict__ W1, const float* __restrict__ b1,
    const float* __restrict__ W2, const float* __restrict__ b2,
    const float* __restrict__ W3, const float* __restrict__ b3,
    const float* __restrict__ W4, const float* __restrict__ b4,
    const float* __restrict__ W5, const float* __restrict__ b5,
    float* __restrict__ y, double* __restrict__ Rp)
{
    __shared__ __align__(16) float sW1T[400], sW2T[400], sW3T[400], sW4T[200];
    __shared__ float sW5[10], sb1[20], sb2[20], sb3[20], sb4[10], sb5v[1];
    __shared__ double rbuf[TPB];

    const int tid = threadIdx.x;
    for (int i = tid; i < 400; i += TPB) {
        const int j = i / 20, c = i % 20;
        sW1T[i] = W1[c * 20 + j];
        sW2T[i] = W2[c * 20 + j];
        sW3T[i] = W3[c * 20 + j];
    }
    if (tid < 200) { const int j = tid / 20, c = tid % 20; sW4T[tid] = W4[c * 10 + j]; }
    if (tid < 20) { sb1[tid] = b1[tid]; sb2[tid] = b2[tid]; sb3[tid] = b3[tid]; }
    if (tid < 10) { sW5[tid] = W5[tid]; sb4[tid] = b4[tid]; }
    if (tid == 0) sb5v[0] = b5[0];
    __syncthreads();

    const int bs = blockIdx.x >> 2;                  // row index b*S+s
    const int qt = blockIdx.x & 3;                   // quarter of the row
    const float* base = data + (size_t)bs * Cn * Tn; // [c][t]
    const int t0 = qt * (Tn / 4) + tid * 2;

    float x[2][20], h[2][20];
    #pragma unroll
    for (int c = 0; c < 20; ++c) {
        const float2 v = *(const float2*)&base[c * Tn + t0];
        x[0][c] = v.x; x[1][c] = v.y;
    }

    layer2<20>(x, h, sW1T, sb1);
    layer2<20>(h, x, sW2T, sb2);
    layer2<20>(x, h, sW3T, sb3);
    layer2<10>(h, x, sW4T, sb4);

    float yv[2];
    #pragma unroll
    for (int m = 0; m < 2; ++m) {   // 10 -> 1
        float yy = sb5v[0];
        #pragma unroll
        for (int i = 0; i < 10; ++i) yy = fmaf(x[m][i], sW5[i], yy);
        yv[m] = fmaxf(yy, 0.f);
    }
    float2 st; st.x = yv[0]; st.y = yv[1];
    *(float2*)&y[(size_t)bs * Tn + t0] = st;

    // block partial row-sum (fp64)
    rbuf[tid] = (double)yv[0] + (double)yv[1];
    __syncthreads();
    for (int off = 128; off > 0; off >>= 1) {
        if (tid < off) rbuf[tid] += rbuf[tid + off];
        __syncthreads();
    }
    if (tid == 0) Rp[blockIdx.x] = rbuf[0];
}

// ---------------- Kernel B: covariance. grid = B*S*4; block -> 16 u's of row s ----------------
__global__ __launch_bounds__(256) void cov_kernel(
    const float* __restrict__ y, const double* __restrict__ Rp,
    double* __restrict__ covd)
{
    __shared__ __align__(16) float ysc[Tn];   // centered row s, fp32 (8 KB)
    __shared__ double rbuf[TPB];

    const int tid = threadIdx.x;
    const int lane = tid & 63, wv = tid >> 6;
    const int ut = blockIdx.x & 3;
    const int bs = blockIdx.x >> 2;          // b*64+s
    const int b = bs >> 6;

    const double ms = (Rp[bs * 4] + Rp[bs * 4 + 1] + Rp[bs * 4 + 2] + Rp[bs * 4 + 3]) * (1.0 / Tn);
    const float* yrow = y + (size_t)bs * Tn;

    double lsum = 0.0;
    for (int t = tid; t < Tn; t += TPB) {
        const float v = (float)((double)yrow[t] - ms);
        ysc[t] = v;
        lsum += (double)v;
    }
    rbuf[tid] = lsum;
    __syncthreads();
    for (int off = 128; off > 0; off >>= 1) {
        if (tid < off) rbuf[tid] += rbuf[tid + off];
        __syncthreads();
    }
    const double sumYsc = rbuf[0];   // residual sum of centered row (≈0)

    const float* ybase = y + (size_t)(b << 6) * Tn;
    const double* Rb = Rp + (b << 6) * 4;
    double* crow = covd + (size_t)bs * Sn;

    #pragma unroll
    for (int uu = 0; uu < 4; ++uu) {
        const int u = ut * 16 + wv * 4 + uu;
        const float* yu = ybase + (size_t)u * Tn;
        float acc = 0.f;
        #pragma unroll
        for (int k = 0; k < Tn / 256; ++k) {         // 8 iterations, 4 elems each
            const int t = (k * 64 + lane) * 4;
            const float4 a = *(const float4*)&ysc[t];   // ds_read_b128
            const float4 g = *(const float4*)&yu[t];    // global dwordx4
            acc = fmaf(a.x, g.x, acc);
            acc = fmaf(a.y, g.y, acc);
            acc = fmaf(a.z, g.z, acc);
            acc = fmaf(a.w, g.w, acc);
        }
        #pragma unroll
        for (int off = 32; off; off >>= 1) acc += __shfl_down(acc, off, 64);
        if (lane == 0) {
            const double mu = (Rb[u * 4] + Rb[u * 4 + 1] + Rb[u * 4 + 2] + Rb[u * 4 + 3]) * (1.0 / Tn);
            crow[u] = ((double)acc - mu * sumYsc) * (1.0 / (Tn - 1));
        }
    }
}

// ---------------- Kernel C: corr + output (fp64, NaN-propagating clip) ----------------
__global__ __launch_bounds__(256) void corr_kernel(
    const double* __restrict__ covd, float* __restrict__ out)
{
    const int i = blockIdx.x * TPB + threadIdx.x;
    if (i >= Bn * Sn * Sn) return;
    const int b = i / (Sn * Sn);
    const int rem = i % (Sn * Sn);
    const int s = rem / Sn, u = rem % Sn;
    const double css = covd[((size_t)b * Sn + s) * Sn + s];
    const double cuu = covd[((size_t)b * Sn + u) * Sn + u];
    const double csu = covd[i];
    double r = csu / sqrt(css * cuu);
    r = (r < -1.0) ? -1.0 : ((r > 1.0) ? 1.0 : r);   // NaN-propagating clip
    out[i] = (float)(1.0 - r);
}

extern "C" void kernel_launch(void* const* d_in, const int* in_sizes, int n_in,
                              void* d_out, int out_size, void* d_ws, size_t ws_size,
                              hipStream_t stream) {
    const float* data = (const float*)d_in[0];
    const float* W1 = (const float*)d_in[1];  const float* b1 = (const float*)d_in[2];
    const float* W2 = (const float*)d_in[3];  const float* b2 = (const float*)d_in[4];
    const float* W3 = (const float*)d_in[5];  const float* b3 = (const float*)d_in[6];
    const float* W4 = (const float*)d_in[7];  const float* b4 = (const float*)d_in[8];
    const float* W5 = (const float*)d_in[9];  const float* b5 = (const float*)d_in[10];
    float* out = (float*)d_out;

    // ws layout: y fp32 (8 MB) | covd fp64 (512 KB) | Rp fp64 (32 KB)
    float* y = (float*)d_ws;
    double* covd = (double*)((char*)d_ws + (size_t)Bn * Sn * Tn * sizeof(float));
    double* Rp = covd + (size_t)Bn * Sn * Sn;

    mlp_kernel<<<Bn * Sn * 4, TPB, 0, stream>>>(data, W1, b1, W2, b2, W3, b3, W4, b4, W5, b5, y, Rp);
    cov_kernel<<<Bn * Sn * 4, TPB, 0, stream>>>(y, Rp, covd);
    corr_kernel<<<(Bn * Sn * Sn + TPB - 1) / TPB, TPB, 0, stream>>>(covd, out);
}

// Round 8
// 302.816 us; speedup vs baseline: 1.4288x; 1.0442x over previous
//
#include <hip/hip_runtime.h>

#define Bn 16
#define Sn 64
#define Cn 20
#define Tn 2048
#define TPB 256
#define KS 8            // K-slices
#define Kc (Tn / KS)    // 256
#define PITCH 260       // LDS row pitch in words (16B-aligned, conflict-friendly)

// One MLP layer for 2 time points: in[m][c] -> out[m][j], ReLU.
// WT transposed in LDS: WT[j*20+c], rows 80 B (16B-aligned) -> ds_read_b128.
template <int NJ>
__device__ __forceinline__ void layer2(const float (&in)[2][20], float (&out)[2][20],
                                       const float* __restrict__ WT,
                                       const float* __restrict__ bb) {
    #pragma unroll
    for (int j = 0; j < NJ; ++j) {
        float a0 = bb[j], a1 = bb[j];
        const float4* wr = (const float4*)(WT + j * 20);
        #pragma unroll
        for (int q = 0; q < 5; ++q) {
            const float4 w = wr[q];
            a0 = fmaf(in[0][4 * q + 0], w.x, a0);  a1 = fmaf(in[1][4 * q + 0], w.x, a1);
            a0 = fmaf(in[0][4 * q + 1], w.y, a0);  a1 = fmaf(in[1][4 * q + 1], w.y, a1);
            a0 = fmaf(in[0][4 * q + 2], w.z, a0);  a1 = fmaf(in[1][4 * q + 2], w.z, a1);
            a0 = fmaf(in[0][4 * q + 3], w.w, a0);  a1 = fmaf(in[1][4 * q + 3], w.w, a1);
        }
        out[0][j] = fmaxf(a0, 0.f);
        out[1][j] = fmaxf(a1, 0.f);
    }
}

// ---------------- Kernel A: MLP (unchanged from R7). grid = B*S*4 ----------------
__global__ __launch_bounds__(256) void mlp_kernel(
    const float* __restrict__ data,
    const float* __restrict__ W1, const float* __restrict__ b1,
    const float* __restrict__ W2, const float* __restrict__ b2,
    const float* __restrict__ W3, const float* __restrict__ b3,
    const float* __restrict__ W4, const float* __restrict__ b4,
    const float* __restrict__ W5, const float* __restrict__ b5,
    float* __restrict__ y, double* __restrict__ Rp)
{
    __shared__ __align__(16) float sW1T[400], sW2T[400], sW3T[400], sW4T[200];
    __shared__ float sW5[10], sb1[20], sb2[20], sb3[20], sb4[10], sb5v[1];
    __shared__ double rbuf[TPB];

    const int tid = threadIdx.x;
    for (int i = tid; i < 400; i += TPB) {
        const int j = i / 20, c = i % 20;
        sW1T[i] = W1[c * 20 + j];
        sW2T[i] = W2[c * 20 + j];
        sW3T[i] = W3[c * 20 + j];
    }
    if (tid < 200) { const int j = tid / 20, c = tid % 20; sW4T[tid] = W4[c * 10 + j]; }
    if (tid < 20) { sb1[tid] = b1[tid]; sb2[tid] = b2[tid]; sb3[tid] = b3[tid]; }
    if (tid < 10) { sW5[tid] = W5[tid]; sb4[tid] = b4[tid]; }
    if (tid == 0) sb5v[0] = b5[0];
    __syncthreads();

    const int bs = blockIdx.x >> 2;
    const int qt = blockIdx.x & 3;
    const float* base = data + (size_t)bs * Cn * Tn;
    const int t0 = qt * (Tn / 4) + tid * 2;

    float x[2][20], h[2][20];
    #pragma unroll
    for (int c = 0; c < 20; ++c) {
        const float2 v = *(const float2*)&base[c * Tn + t0];
        x[0][c] = v.x; x[1][c] = v.y;
    }

    layer2<20>(x, h, sW1T, sb1);
    layer2<20>(h, x, sW2T, sb2);
    layer2<20>(x, h, sW3T, sb3);
    layer2<10>(h, x, sW4T, sb4);

    float yv[2];
    #pragma unroll
    for (int m = 0; m < 2; ++m) {
        float yy = sb5v[0];
        #pragma unroll
        for (int i = 0; i < 10; ++i) yy = fmaf(x[m][i], sW5[i], yy);
        yv[m] = fmaxf(yy, 0.f);
    }
    float2 st; st.x = yv[0]; st.y = yv[1];
    *(float2*)&y[(size_t)bs * Tn + t0] = st;

    rbuf[tid] = (double)yv[0] + (double)yv[1];
    __syncthreads();
    for (int off = 128; off > 0; off >>= 1) {
        if (tid < off) rbuf[tid] += rbuf[tid + off];
        __syncthreads();
    }
    if (tid == 0) Rp[blockIdx.x] = rbuf[0];
}

// ---------------- Kernel B: Gram via K-split GEMM tile + fp32 atomics ----------------
// grid = Bn * KS blocks; block stages 64 rows x Kc centered fp32 in LDS,
// each thread computes a 4x4 tile of the 64x64 Gram partial, atomicAdds to covf.
__global__ __launch_bounds__(256) void cov_kernel(
    const float* __restrict__ y, const double* __restrict__ Rp,
    float* __restrict__ covf)
{
    __shared__ __align__(16) float S[64 * PITCH];   // ~65 KB
    __shared__ double smean[64];

    const int tid = threadIdx.x;
    const int b  = blockIdx.x >> 3;
    const int ks = blockIdx.x & 7;

    if (tid < 64) {
        const int q = ((b << 6) + tid) * 4;
        smean[tid] = (Rp[q] + Rp[q + 1] + Rp[q + 2] + Rp[q + 3]) * (1.0 / Tn);
    }
    __syncthreads();

    // stage: 64 rows x Kc floats, centered (fp64 mean), fp32 in LDS
    const float* ybase = y + (size_t)(b << 6) * Tn + ks * Kc;
    #pragma unroll
    for (int it = 0; it < (64 * Kc / 4) / TPB; ++it) {   // 16 iters
        const int f4 = tid + it * TPB;
        const int row = f4 >> 6;                          // Kc/4 = 64 float4 per row
        const int k4 = f4 & 63;
        const float4 v = *(const float4*)&ybase[(size_t)row * Tn + k4 * 4];
        const double m = smean[row];
        float4 c;
        c.x = (float)((double)v.x - m);
        c.y = (float)((double)v.y - m);
        c.z = (float)((double)v.z - m);
        c.w = (float)((double)v.w - m);
        *(float4*)&S[row * PITCH + k4 * 4] = c;
    }
    __syncthreads();

    // compute: thread (ty,tx) -> rows {ty+16a}, cols {tx+16j}
    const int ty = tid >> 4, tx = tid & 15;
    float acc[4][4];
    #pragma unroll
    for (int a = 0; a < 4; ++a)
        #pragma unroll
        for (int j = 0; j < 4; ++j) acc[a][j] = 0.f;

    for (int kq = 0; kq < Kc / 4; ++kq) {
        float4 av[4], bv[4];
        #pragma unroll
        for (int a = 0; a < 4; ++a) av[a] = *(const float4*)&S[(ty + 16 * a) * PITCH + kq * 4];
        #pragma unroll
        for (int j = 0; j < 4; ++j) bv[j] = *(const float4*)&S[(tx + 16 * j) * PITCH + kq * 4];
        #pragma unroll
        for (int a = 0; a < 4; ++a)
            #pragma unroll
            for (int j = 0; j < 4; ++j) {
                acc[a][j] = fmaf(av[a].x, bv[j].x, acc[a][j]);
                acc[a][j] = fmaf(av[a].y, bv[j].y, acc[a][j]);
                acc[a][j] = fmaf(av[a].z, bv[j].z, acc[a][j]);
                acc[a][j] = fmaf(av[a].w, bv[j].w, acc[a][j]);
            }
    }

    float* cb = covf + ((size_t)b << 12);
    #pragma unroll
    for (int a = 0; a < 4; ++a) {
        const int row = ty + 16 * a;
        #pragma unroll
        for (int j = 0; j < 4; ++j)
            atomicAdd(&cb[(row << 6) + tx + 16 * j], acc[a][j]);
    }
}

// ---------------- Kernel C: corr + output (fp64 ratio, NaN-propagating clip) ----------------
// Note: covf is the UNSCALED Gram (no 1/(T-1)) — the scale cancels in corr.
__global__ __launch_bounds__(256) void corr_kernel(
    const float* __restrict__ covf, float* __restrict__ out)
{
    const int i = blockIdx.x * TPB + threadIdx.x;
    if (i >= Bn * Sn * Sn) return;
    const int b = i / (Sn * Sn);
    const int rem = i % (Sn * Sn);
    const int s = rem / Sn, u = rem % Sn;
    const double css = (double)covf[((size_t)b * Sn + s) * Sn + s];
    const double cuu = (double)covf[((size_t)b * Sn + u) * Sn + u];
    const double csu = (double)covf[i];
    double r = csu / sqrt(css * cuu);
    r = (r < -1.0) ? -1.0 : ((r > 1.0) ? 1.0 : r);   // NaN-propagating clip
    out[i] = (float)(1.0 - r);
}

extern "C" void kernel_launch(void* const* d_in, const int* in_sizes, int n_in,
                              void* d_out, int out_size, void* d_ws, size_t ws_size,
                              hipStream_t stream) {
    const float* data = (const float*)d_in[0];
    const float* W1 = (const float*)d_in[1];  const float* b1 = (const float*)d_in[2];
    const float* W2 = (const float*)d_in[3];  const float* b2 = (const float*)d_in[4];
    const float* W3 = (const float*)d_in[5];  const float* b3 = (const float*)d_in[6];
    const float* W4 = (const float*)d_in[7];  const float* b4 = (const float*)d_in[8];
    const float* W5 = (const float*)d_in[9];  const float* b5 = (const float*)d_in[10];
    float* out = (float*)d_out;

    // ws layout: y fp32 (8 MB) | covf fp32 (256 KB) | Rp fp64 (32 KB)  — 8.28 MB total
    float* y = (float*)d_ws;
    float* covf = (float*)((char*)d_ws + (size_t)Bn * Sn * Tn * sizeof(float));
    double* Rp = (double*)((char*)covf + (size_t)Bn * Sn * Sn * sizeof(float));

    hipMemsetAsync(covf, 0, (size_t)Bn * Sn * Sn * sizeof(float), stream);
    mlp_kernel<<<Bn * Sn * 4, TPB, 0, stream>>>(data, W1, b1, W2, b2, W3, b3, W4, b4, W5, b5, y, Rp);
    cov_kernel<<<Bn * KS, TPB, 0, stream>>>(y, Rp, covf);
    corr_kernel<<<(Bn * Sn * Sn + TPB - 1) / TPB, TPB, 0, stream>>>(covf, out);
}